// Round 16
// baseline (684.824 us; speedup 1.0000x reference)
//
#include <hip/hip_runtime.h>

#define NGRAPH 100
#define NPER   1000
#define NNODES 100000
#define NEDGES 1600000
#define EPG    16000   // edges per graph

typedef float v2f __attribute__((ext_vector_type(2)));

// DPP-based add of a permuted lane within a 16-lane row; VALU latency.
template <int CTRL>
__device__ __forceinline__ float dpp_add(float x) {
    int yi = __builtin_amdgcn_update_dpp(0, __float_as_int(x), CTRL, 0xF, 0xF, true);
    return x + __int_as_float(yi);
}
#define DPP_XOR1 0xB1   // quad_perm [1,0,3,2]
#define DPP_XOR2 0x4E   // quad_perm [2,3,0,1]
#define DPP_HMIR 0x141  // row_half_mirror: completes an 8-lane sum

// bf16x2 (packed in u32) -> 2 floats
__device__ __forceinline__ v2f bf2f(unsigned u) {
    v2f r;
    r.x = __uint_as_float(u << 16);
    r.y = __uint_as_float(u & 0xffff0000u);
    return r;
}
// 2 floats -> bf16x2 (round-to-nearest-ish)
__device__ __forceinline__ unsigned pkbf(float a, float b) {
    unsigned ua = (__float_as_uint(a) + 0x8000u) >> 16;
    unsigned ub = (__float_as_uint(b) + 0x8000u) & 0xffff0000u;
    return ua | ub;
}

// dual-node 4-channel dot: a/c over nodes A/B, weights stride STRIDE floats
template <int STRIDE>
__device__ __forceinline__ void dot2x4(const float* __restrict__ w,
                                       const float* hA, const float* hB,
                                       float4& a, float4& c) {
    a = make_float4(0.f, 0.f, 0.f, 0.f);
    c = make_float4(0.f, 0.f, 0.f, 0.f);
    #pragma unroll 4
    for (int d = 0; d < 32; d++) {
        float4 wv = *(const float4*)(w + d * STRIDE);
        a.x = fmaf(hA[d], wv.x, a.x);  c.x = fmaf(hB[d], wv.x, c.x);
        a.y = fmaf(hA[d], wv.y, a.y);  c.y = fmaf(hB[d], wv.y, c.y);
        a.z = fmaf(hA[d], wv.z, a.z);  c.z = fmaf(hB[d], wv.z, c.z);
        a.w = fmaf(hA[d], wv.w, a.w);  c.w = fmaf(hB[d], wv.w, c.w);
    }
}

// ==================== utility: zero count + g_acc in one launch ============
__global__ __launch_bounds__(256) void zero2_k(int* __restrict__ count,
                                               float* __restrict__ g_acc) {
    int i = blockIdx.x * 256 + threadIdx.x;
    if (i < NNODES) count[i] = 0;
    if (i < NGRAPH * 96) g_acc[i] = 0.f;
}

// ==================== counting sort of edges by DST ====================
__global__ __launch_bounds__(256) void hist_k(const int* __restrict__ dst,
                                              int* __restrict__ count) {
    int e = blockIdx.x * 256 + threadIdx.x;
    if (e < NEDGES) atomicAdd(&count[dst[e]], 1);
}

__global__ __launch_bounds__(1024) void scan_k(const int* __restrict__ count,
                                               int* __restrict__ offs,
                                               int* __restrict__ cursor) {
    __shared__ int sc[1024];
    int t = threadIdx.x, g = blockIdx.x;
    int v = (t < NPER) ? count[g * NPER + t] : 0;
    sc[t] = v;
    __syncthreads();
    for (int s = 1; s < 1024; s <<= 1) {
        int add = (t >= s) ? sc[t - s] : 0;
        __syncthreads();
        sc[t] += add;
        __syncthreads();
    }
    if (t < NPER) {
        int start = g * EPG + sc[t] - v;   // exclusive
        offs[g * NPER + t]   = start;
        cursor[g * NPER + t] = start;
    }
}

// record: {src, etype | elabel<<16}
__global__ __launch_bounds__(256) void scatter_k(
    const int* __restrict__ src, const int* __restrict__ dst,
    const int* __restrict__ et, const int* __restrict__ el,
    int* __restrict__ cursor, int2* __restrict__ sorted2) {
    int e = blockIdx.x * 256 + threadIdx.x;
    if (e >= NEDGES) return;
    int d = dst[e];
    int p = atomicAdd(&cursor[d], 1);
    sorted2[p] = make_int2(src[e], et[e] | (el[e] << 16));
}

// ==================== node projections: 2 nodes/thread, quad-major outs ====
// grid (196, 5). Thread t owns nodes 2t, 2t+1.
// Quad-major layouts (edge lane ci indexes region ci with 32-bit voffset):
//   xbq : uint4[8 regions][NNODES*2]   region r=y*4+q; per node 2 uint4 (bf16)
//   psq/pdq/sfq : float4[8 regions][NNODES]
// y=0: xproj quads 0..3 (ch 0..15)   y=1: quads 4..7
// y=2: psq+pdq   y=3: sfq   y=4: rel tables
__global__ __launch_bounds__(256, 4) void node_k(
    const float* __restrict__ h, const float* __restrict__ basis_l,
    const float* __restrict__ selfw_l, const float* __restrict__ Aw_l,
    const float* __restrict__ Ab_l, const float* __restrict__ attn_tab,
    uint4* __restrict__ xbq, float4* __restrict__ psq,
    float4* __restrict__ pdq, float4* __restrict__ sfq,
    unsigned* __restrict__ t1b, unsigned* __restrict__ t2b)
{
    const int y = blockIdx.y;
    if (y == 4) {   // rel tables: r = bid*4 + wave
        int r = blockIdx.x * 4 + (threadIdx.x >> 6);
        if (r >= 200) return;
        int t = threadIdx.x & 63;
        int o = t & 31;
        bool second = t >= 32;
        const float* at = attn_tab + r * 32;
        const float* W  = Aw_l + (second ? 96*32 : 64*32);
        float acc = second ? 0.f : Ab_l[o];
        #pragma unroll 8
        for (int d = 0; d < 32; d++) acc += at[d] * W[d*32 + o];
        float nb = __shfl_down(acc, 1);
        unsigned u = pkbf(acc, nb);
        if (!(o & 1)) (second ? t2b : t1b)[r*16 + (o >> 1)] = u;
        return;
    }

    __shared__ float w_s[2048];
    if (y < 2) {
        // basis channels [y*16, y*16+16): w_s[b*512 + d*16 + c]
        for (int k = threadIdx.x; k < 2048; k += 256) {
            int b = k >> 9, rem = k & 511, d = rem >> 4, c = rem & 15;
            w_s[k] = basis_l[b*1024 + d*32 + y*16 + c];
        }
    } else if (y == 2) {
        for (int k = threadIdx.x; k < 2048; k += 256) w_s[k] = Aw_l[k]; // A1|A2
    } else {
        for (int k = threadIdx.x; k < 1024; k += 256) w_s[k] = selfw_l[k];
    }
    __syncthreads();

    int t = blockIdx.x * 256 + threadIdx.x;
    int nA = t * 2;
    if (nA >= NNODES) return;
    int nB = nA + 1;

    float hA[32], hB[32];
    {
        const float4* hpA = (const float4*)(h + nA * 32);
        const float4* hpB = (const float4*)(h + nB * 32);
        #pragma unroll
        for (int k = 0; k < 8; k++) {
            float4 a = hpA[k], b = hpB[k];
            hA[4*k+0]=a.x; hA[4*k+1]=a.y; hA[4*k+2]=a.z; hA[4*k+3]=a.w;
            hB[4*k+0]=b.x; hB[4*k+1]=b.y; hB[4*k+2]=b.z; hB[4*k+3]=b.w;
        }
    }

    if (y < 2) {
        #pragma unroll 1
        for (int q = 0; q < 4; q++) {
            float4 pA[4], pB[4];
            #pragma unroll 1
            for (int b = 0; b < 4; b++)
                dot2x4<16>(w_s + b * 512 + q * 4, hA, hB, pA[b], pB[b]);
            // region r = y*4+q; 4 consecutive uint4 (64B) back-to-back
            uint4* o = xbq + (y*4 + q) * (NNODES*2) + nA*2;
            o[0] = make_uint4(pkbf(pA[0].x,pA[0].y), pkbf(pA[1].x,pA[1].y),
                              pkbf(pA[2].x,pA[2].y), pkbf(pA[3].x,pA[3].y));
            o[1] = make_uint4(pkbf(pA[0].z,pA[0].w), pkbf(pA[1].z,pA[1].w),
                              pkbf(pA[2].z,pA[2].w), pkbf(pA[3].z,pA[3].w));
            o[2] = make_uint4(pkbf(pB[0].x,pB[0].y), pkbf(pB[1].x,pB[1].y),
                              pkbf(pB[2].x,pB[2].y), pkbf(pB[3].x,pB[3].y));
            o[3] = make_uint4(pkbf(pB[0].z,pB[0].w), pkbf(pB[1].z,pB[1].w),
                              pkbf(pB[2].z,pB[2].w), pkbf(pB[3].z,pB[3].w));
        }
    } else if (y == 2) {
        #pragma unroll 1
        for (int m = 0; m < 2; m++) {
            float4* outp = (m == 0 ? psq : pdq);
            #pragma unroll 1
            for (int oc = 0; oc < 8; oc++) {
                float4 a, c;
                dot2x4<32>(w_s + m * 1024 + oc * 4, hA, hB, a, c);
                outp[oc*NNODES + nA] = a;      // adjacent lanes -> contiguous
                outp[oc*NNODES + nB] = c;
            }
        }
    } else {
        #pragma unroll 1
        for (int oc = 0; oc < 8; oc++) {
            float4 a, c;
            dot2x4<32>(w_s + oc * 4, hA, hB, a, c);
            sfq[oc*NNODES + nA] = a;
            sfq[oc*NNODES + nB] = c;
        }
    }
}

// ==================== CSR edge kernel: 8 lanes/edge, 4 ch/lane =============
// R14-validated gather-instruction-bound structure. Quad-major operands:
// lane ci reads region ci -> uniform SGPR base + 32-bit voffset (SADDR).
__global__ __launch_bounds__(256) void edge_csr_k(
    const int2* __restrict__ sorted2, const int* __restrict__ offs,
    const float4* __restrict__ psq, const float4* __restrict__ pdq,
    const unsigned* __restrict__ t1b, const unsigned* __restrict__ t2b,
    const uint4* __restrict__ xbq, const float4* __restrict__ sfq,
    const float* __restrict__ wcomp_l,
    const float* __restrict__ Bw, const float* __restrict__ Bb,
    float* __restrict__ h_next)
{
    // XCD-bijective swizzle: 25000 blocks, 25000 % 8 == 0.
    const int CPX = 25000 / 8;
    int bid = (int)blockIdx.x;
    bid = (bid % 8) * CPX + bid / 8;

    const int wib  = threadIdx.x >> 6;   // wave in block: 0..3
    const int lane = threadIdx.x & 63;
    const int grp  = lane >> 3;          // edge slot 0..7
    const int ci   = lane & 7;           // channel quad 0..7
    const int c4   = ci * 4;
    const int n    = bid * 4 + wib;      // dst node
    const int ciN  = ci * NNODES;        // lane-constant region offset

    const int start = offs[n];
    const int end   = (n == NNODES - 1) ? NEDGES : offs[n + 1];
    const float4 bw = *(const float4*)(Bw + c4);
    const float bb = Bb[0];
    const float4 pd = pdq[ciN + n];

    int e = start + grp;
    int2 rec = sorted2[(e < end) ? e : start];
    bool valid = (e < end);

    v2f acc01 = {0.f, 0.f}, acc23 = {0.f, 0.f};
    for (int e0 = start; e0 < end; e0 += 8) {
        int2 cur = rec;
        bool cv = valid;
        int en = e + 8;
        valid = (en < end);
        rec = sorted2[valid ? en : start];
        e = en;

        int u  = ciN + cur.x;        // region + src
        int et = cur.y & 0xffff;
        int el = cur.y >> 16;

        float4 ps  = psq[u];
        uint4  xlo = xbq[u * 2];
        uint4  xhi = xbq[u * 2 + 1];
        uint2  t1u = *(const uint2*)(t1b + et * 16 + ci * 2);
        uint2  t2u = *(const uint2*)(t2b + el * 16 + ci * 2);
        float4 c   = *(const float4*)(wcomp_l + et * 4);

        v2f t1a = bf2f(t1u.x), t1c = bf2f(t1u.y);
        v2f t2a = bf2f(t2u.x), t2c = bf2f(t2u.y);
        float z0 = fmaxf(ps.x + pd.x + t1a.x + t2a.x, 0.f);
        float z1 = fmaxf(ps.y + pd.y + t1a.y + t2a.y, 0.f);
        float z2 = fmaxf(ps.z + pd.z + t1c.x + t2c.x, 0.f);
        float z3 = fmaxf(ps.w + pd.w + t1c.y + t2c.y, 0.f);
        float d = fmaf(z0, bw.x, fmaf(z1, bw.y, fmaf(z2, bw.z, z3 * bw.w)));
        d = dpp_add<DPP_XOR1>(d);
        d = dpp_add<DPP_XOR2>(d);
        d = dpp_add<DPP_HMIR>(d);
        float a = __builtin_amdgcn_rcpf(1.f + __expf(-(d + bb)));
        a = cv ? a : 0.f;

        v2f b0 = bf2f(xlo.x), b1 = bf2f(xlo.y), b2 = bf2f(xlo.z), b3 = bf2f(xlo.w);
        v2f m01 = c.x * b0 + c.y * b1 + c.z * b2 + c.w * b3;
        v2f g0 = bf2f(xhi.x), g1 = bf2f(xhi.y), g2 = bf2f(xhi.z), g3 = bf2f(xhi.w);
        v2f m23 = c.x * g0 + c.y * g1 + c.z * g2 + c.w * g3;
        acc01 += a * m01;
        acc23 += a * m23;
    }
    // reduce across the 8 edge-slots (off the hot loop)
    #pragma unroll
    for (int s = 8; s <= 32; s <<= 1) {
        acc01.x += __shfl_xor(acc01.x, s);
        acc01.y += __shfl_xor(acc01.y, s);
        acc23.x += __shfl_xor(acc23.x, s);
        acc23.y += __shfl_xor(acc23.y, s);
    }
    if (lane < 8) {
        float4 sp = sfq[ciN + n];
        float4 hv;
        hv.x = fmaxf(acc01.x + sp.x, 0.f);
        hv.y = fmaxf(acc01.y + sp.y, 0.f);
        hv.z = fmaxf(acc23.x + sp.z, 0.f);
        hv.w = fmaxf(acc23.y + sp.w, 0.f);
        *(float4*)(h_next + n * 32 + c4) = hv;
    }
}

// ==================== per-graph mean (8 slices) + head/tail (y=8) ==========
__global__ __launch_bounds__(256) void mean_ht_k(
    const float* __restrict__ h, const int* __restrict__ head_ids,
    const int* __restrict__ tail_ids, float* __restrict__ g_acc,
    float* __restrict__ head_buf, float* __restrict__ tail_buf, int l)
{
    int g  = blockIdx.x;
    int sl = blockIdx.y;
    int i  = threadIdx.x & 31;
    if (sl == 8) {
        if (threadIdx.x < 32)
            head_buf[g*96 + l*32 + i] = h[head_ids[g]*32 + i];
        else if (threadIdx.x < 64)
            tail_buf[g*96 + l*32 + i] = h[tail_ids[g]*32 + i];
        return;
    }
    int sub = threadIdx.x >> 5;
    float acc = 0.f;
    for (int k = sub; k < 125; k += 8)
        acc += h[(g*NPER + sl*125 + k)*32 + i];
    __shared__ float red[8][32];
    red[sub][i] = acc;
    __syncthreads();
    if (threadIdx.x < 32) {
        float s2 = 0.f;
        #pragma unroll
        for (int k = 0; k < 8; k++) s2 += red[k][threadIdx.x];
        atomicAdd(&g_acc[g*96 + l*32 + threadIdx.x], s2 * (1.0f/NPER));
    }
}

// ==================== final readout ====================
__global__ __launch_bounds__(64) void readout_k(
    const float* __restrict__ g_acc, const float* __restrict__ head_buf,
    const float* __restrict__ tail_buf, const float* __restrict__ rel_tab,
    const int* __restrict__ rel_labels, const float* __restrict__ fc_w,
    const float* __restrict__ fc_b, float* __restrict__ out)
{
    int g = blockIdx.x;
    int t = threadIdx.x;
    float s = 0.f;
    for (int idx = t; idx < 320; idx += 64) {
        float v;
        if (idx < 96)       v = g_acc[g*96 + idx];
        else if (idx < 192) v = head_buf[g*96 + idx - 96];
        else if (idx < 288) v = tail_buf[g*96 + idx - 192];
        else                v = rel_tab[rel_labels[g]*32 + (idx - 288)];
        s += v * fc_w[idx];
    }
    s += __shfl_xor(s, 1, 64);
    s += __shfl_xor(s, 2, 64);
    s += __shfl_xor(s, 4, 64);
    s += __shfl_xor(s, 8, 64);
    s += __shfl_xor(s, 16, 64);
    s += __shfl_xor(s, 32, 64);
    if (t == 0) out[g] = s + fc_b[0];
}

extern "C" void kernel_launch(void* const* d_in, const int* in_sizes, int n_in,
                              void* d_out, int out_size, void* d_ws, size_t ws_size,
                              hipStream_t stream) {
    const float* feat        = (const float*)d_in[0];
    const float* basis       = (const float*)d_in[1];   // [3,4,32,32]
    const float* w_comp      = (const float*)d_in[2];   // [3,200,4]
    const float* self_loop_w = (const float*)d_in[3];   // [3,32,32]
    const float* A_w         = (const float*)d_in[4];   // [3,128,32]
    const float* A_b         = (const float*)d_in[5];   // [3,32]
    const float* B_w         = (const float*)d_in[6];   // [3,32,1]
    const float* B_b         = (const float*)d_in[7];   // [3,1]
    const float* attn_tab    = (const float*)d_in[8];   // [200,32]
    const float* rel_tab     = (const float*)d_in[9];   // [200,32]
    const float* fc_w        = (const float*)d_in[10];  // [320,1]
    const float* fc_b        = (const float*)d_in[11];  // [1]
    const int* src        = (const int*)d_in[12];
    const int* dst        = (const int*)d_in[13];
    const int* etype      = (const int*)d_in[14];
    const int* elabel     = (const int*)d_in[15];
    const int* head_ids   = (const int*)d_in[17];
    const int* tail_ids   = (const int*)d_in[18];
    const int* rel_labels = (const int*)d_in[19];

    float* ws = (float*)d_ws;
    size_t off = 0;
    float* h0    = ws + off; off += (size_t)NNODES * 32;
    float* h1    = ws + off; off += (size_t)NNODES * 32;
    uint4*  xbq = (uint4*)(ws + off);  off += (size_t)NNODES * 64;  // 8 regions x 2 uint4
    float4* psq = (float4*)(ws + off); off += (size_t)NNODES * 32;
    float4* pdq = (float4*)(ws + off); off += (size_t)NNODES * 32;
    float4* sfq = (float4*)(ws + off); off += (size_t)NNODES * 32;
    unsigned* t1b = (unsigned*)(ws + off); off += 3200;
    unsigned* t2b = (unsigned*)(ws + off); off += 3200;
    float* g_acc    = ws + off; off += NGRAPH * 96;
    float* head_buf = ws + off; off += NGRAPH * 96;
    float* tail_buf = ws + off; off += NGRAPH * 96;
    int* count  = (int*)(ws + off); off += NNODES;
    int* offs   = (int*)(ws + off); off += NNODES;
    int* cursor = (int*)(ws + off); off += NNODES;
    off = (off + 3) & ~(size_t)3;               // 16 B align
    int2* sorted2 = (int2*)(ws + off); off += (size_t)NEDGES * 2;

    // ---- one-time per call: CSR by dst + zero mean accumulator ----
    zero2_k<<<(NNODES + 255)/256, 256, 0, stream>>>(count, g_acc);
    hist_k<<<(NEDGES + 255)/256, 256, 0, stream>>>(dst, count);
    scan_k<<<NGRAPH, 1024, 0, stream>>>(count, offs, cursor);
    scatter_k<<<(NEDGES + 255)/256, 256, 0, stream>>>(src, dst, etype, elabel,
                                                      cursor, sorted2);

    const float* hcur = feat;
    float* hbufs[2] = { h0, h1 };
    for (int l = 0; l < 3; l++) {
        dim3 ngrid((NNODES/2 + 255)/256, 5);
        node_k<<<ngrid, 256, 0, stream>>>(
            hcur, basis + (size_t)l*4096, self_loop_w + (size_t)l*1024,
            A_w + (size_t)l*4096, A_b + (size_t)l*32, attn_tab,
            xbq, psq, pdq, sfq, t1b, t2b);
        float* hn = hbufs[l & 1];
        edge_csr_k<<<NNODES/4, 256, 0, stream>>>(
            sorted2, offs, psq, pdq, t1b, t2b, xbq, sfq,
            w_comp + (size_t)l*800, B_w + (size_t)l*32, B_b + l, hn);
        dim3 mgrid(NGRAPH, 9);
        mean_ht_k<<<mgrid, 256, 0, stream>>>(
            hn, head_ids, tail_ids, g_acc, head_buf, tail_buf, l);
        hcur = hn;
    }
    readout_k<<<NGRAPH, 64, 0, stream>>>(
        g_acc, head_buf, tail_buf, rel_tab, rel_labels, fc_w, fc_b, (float*)d_out);
}

// Round 17
// 503.348 us; speedup vs baseline: 1.3605x; 1.3605x over previous
//
#include <hip/hip_runtime.h>

#define NGRAPH 100
#define NPER   1000
#define NNODES 100000
#define NEDGES 1600000
#define EPG    16000   // edges per graph

typedef float v2f __attribute__((ext_vector_type(2)));

// DPP-based add of a permuted lane within a 16-lane row; VALU latency.
template <int CTRL>
__device__ __forceinline__ float dpp_add(float x) {
    int yi = __builtin_amdgcn_update_dpp(0, __float_as_int(x), CTRL, 0xF, 0xF, true);
    return x + __int_as_float(yi);
}
#define DPP_XOR1 0xB1   // quad_perm [1,0,3,2]
#define DPP_XOR2 0x4E   // quad_perm [2,3,0,1]
#define DPP_HMIR 0x141  // row_half_mirror: completes an 8-lane sum

// bf16x2 (packed in u32) -> 2 floats
__device__ __forceinline__ v2f bf2f(unsigned u) {
    v2f r;
    r.x = __uint_as_float(u << 16);
    r.y = __uint_as_float(u & 0xffff0000u);
    return r;
}
// 2 floats -> bf16x2 (round-to-nearest-ish)
__device__ __forceinline__ unsigned pkbf(float a, float b) {
    unsigned ua = (__float_as_uint(a) + 0x8000u) >> 16;
    unsigned ub = (__float_as_uint(b) + 0x8000u) & 0xffff0000u;
    return ua | ub;
}

// dual-node 4-channel dot: a/c over nodes A/B, weights stride STRIDE floats
template <int STRIDE>
__device__ __forceinline__ void dot2x4(const float* __restrict__ w,
                                       const float* hA, const float* hB,
                                       float4& a, float4& c) {
    a = make_float4(0.f, 0.f, 0.f, 0.f);
    c = make_float4(0.f, 0.f, 0.f, 0.f);
    #pragma unroll 4
    for (int d = 0; d < 32; d++) {
        float4 wv = *(const float4*)(w + d * STRIDE);
        a.x = fmaf(hA[d], wv.x, a.x);  c.x = fmaf(hB[d], wv.x, c.x);
        a.y = fmaf(hA[d], wv.y, a.y);  c.y = fmaf(hB[d], wv.y, c.y);
        a.z = fmaf(hA[d], wv.z, a.z);  c.z = fmaf(hB[d], wv.z, c.z);
        a.w = fmaf(hA[d], wv.w, a.w);  c.w = fmaf(hB[d], wv.w, c.w);
    }
}

// ==================== utility: zero count + g_acc in one launch ============
__global__ __launch_bounds__(256) void zero2_k(int* __restrict__ count,
                                               float* __restrict__ g_acc) {
    int i = blockIdx.x * 256 + threadIdx.x;
    if (i < NNODES) count[i] = 0;
    if (i < NGRAPH * 96) g_acc[i] = 0.f;
}

// ==================== counting sort of edges by DST ====================
__global__ __launch_bounds__(256) void hist_k(const int* __restrict__ dst,
                                              int* __restrict__ count) {
    int e = blockIdx.x * 256 + threadIdx.x;
    if (e < NEDGES) atomicAdd(&count[dst[e]], 1);
}

__global__ __launch_bounds__(1024) void scan_k(const int* __restrict__ count,
                                               int* __restrict__ offs,
                                               int* __restrict__ cursor) {
    __shared__ int sc[1024];
    int t = threadIdx.x, g = blockIdx.x;
    int v = (t < NPER) ? count[g * NPER + t] : 0;
    sc[t] = v;
    __syncthreads();
    for (int s = 1; s < 1024; s <<= 1) {
        int add = (t >= s) ? sc[t - s] : 0;
        __syncthreads();
        sc[t] += add;
        __syncthreads();
    }
    if (t < NPER) {
        int start = g * EPG + sc[t] - v;   // exclusive
        offs[g * NPER + t]   = start;
        cursor[g * NPER + t] = start;
    }
}

// compressed record: {src*16, etype | elabel<<16}
__global__ __launch_bounds__(256) void scatter_k(
    const int* __restrict__ src, const int* __restrict__ dst,
    const int* __restrict__ et, const int* __restrict__ el,
    int* __restrict__ cursor, int2* __restrict__ sorted2) {
    int e = blockIdx.x * 256 + threadIdx.x;
    if (e >= NEDGES) return;
    int d = dst[e];
    int p = atomicAdd(&cursor[d], 1);
    sorted2[p] = make_int2(src[e] * 16, et[e] | (el[e] << 16));
}

// ==================== node projections: 2 nodes/thread, node-major outs ====
// grid (196, 5). Thread t owns nodes 2t, 2t+1. Outputs are NODE-MAJOR
// (R16 lesson: quad-major scatters an edge's lanes across distant lines):
//   xproj_b: uint4[NNODES*16]  node row = 256B; quad q at n*16+q*2+{0,1}
//   psrc/pdst/selfp: float[NNODES*32] full 128B rows
// y=0: xproj quads 0..3 (ch 0..15)  y=1: quads 4..7 (disjoint 128B halves)
// y=2: psrc+pdst rows   y=3: selfp rows   y=4: rel tables
__global__ __launch_bounds__(256, 4) void node_k(
    const float* __restrict__ h, const float* __restrict__ basis_l,
    const float* __restrict__ selfw_l, const float* __restrict__ Aw_l,
    const float* __restrict__ Ab_l, const float* __restrict__ attn_tab,
    uint4* __restrict__ xproj_b, float* __restrict__ psrc,
    float* __restrict__ pdst, float* __restrict__ selfp,
    unsigned* __restrict__ t1b, unsigned* __restrict__ t2b)
{
    const int y = blockIdx.y;
    if (y == 4) {   // rel tables: r = bid*4 + wave
        int r = blockIdx.x * 4 + (threadIdx.x >> 6);
        if (r >= 200) return;
        int t = threadIdx.x & 63;
        int o = t & 31;
        bool second = t >= 32;
        const float* at = attn_tab + r * 32;
        const float* W  = Aw_l + (second ? 96*32 : 64*32);
        float acc = second ? 0.f : Ab_l[o];
        #pragma unroll 8
        for (int d = 0; d < 32; d++) acc += at[d] * W[d*32 + o];
        float nb = __shfl_down(acc, 1);
        unsigned u = pkbf(acc, nb);
        if (!(o & 1)) (second ? t2b : t1b)[r*16 + (o >> 1)] = u;
        return;
    }

    __shared__ float w_s[2048];
    if (y < 2) {
        // basis channels [y*16, y*16+16): w_s[b*512 + d*16 + c]
        for (int k = threadIdx.x; k < 2048; k += 256) {
            int b = k >> 9, rem = k & 511, d = rem >> 4, c = rem & 15;
            w_s[k] = basis_l[b*1024 + d*32 + y*16 + c];
        }
    } else if (y == 2) {
        for (int k = threadIdx.x; k < 2048; k += 256) w_s[k] = Aw_l[k]; // A1|A2
    } else {
        for (int k = threadIdx.x; k < 1024; k += 256) w_s[k] = selfw_l[k];
    }
    __syncthreads();

    int t = blockIdx.x * 256 + threadIdx.x;
    int nA = t * 2;
    if (nA >= NNODES) return;
    int nB = nA + 1;

    float hA[32], hB[32];
    {
        const float4* hpA = (const float4*)(h + nA * 32);
        const float4* hpB = (const float4*)(h + nB * 32);
        #pragma unroll
        for (int k = 0; k < 8; k++) {
            float4 a = hpA[k], b = hpB[k];
            hA[4*k+0]=a.x; hA[4*k+1]=a.y; hA[4*k+2]=a.z; hA[4*k+3]=a.w;
            hB[4*k+0]=b.x; hB[4*k+1]=b.y; hB[4*k+2]=b.z; hB[4*k+3]=b.w;
        }
    }

    if (y < 2) {
        #pragma unroll 1
        for (int q = 0; q < 4; q++) {
            float4 pA[4], pB[4];
            #pragma unroll 1
            for (int b = 0; b < 4; b++)
                dot2x4<16>(w_s + b * 512 + q * 4, hA, hB, pA[b], pB[b]);
            const int qg = y * 4 + q;            // global quad 0..7
            uint4* oA = xproj_b + nA * 16 + qg * 2;
            uint4* oB = xproj_b + nB * 16 + qg * 2;
            oA[0] = make_uint4(pkbf(pA[0].x,pA[0].y), pkbf(pA[1].x,pA[1].y),
                               pkbf(pA[2].x,pA[2].y), pkbf(pA[3].x,pA[3].y));
            oA[1] = make_uint4(pkbf(pA[0].z,pA[0].w), pkbf(pA[1].z,pA[1].w),
                               pkbf(pA[2].z,pA[2].w), pkbf(pA[3].z,pA[3].w));
            oB[0] = make_uint4(pkbf(pB[0].x,pB[0].y), pkbf(pB[1].x,pB[1].y),
                               pkbf(pB[2].x,pB[2].y), pkbf(pB[3].x,pB[3].y));
            oB[1] = make_uint4(pkbf(pB[0].z,pB[0].w), pkbf(pB[1].z,pB[1].w),
                               pkbf(pB[2].z,pB[2].w), pkbf(pB[3].z,pB[3].w));
        }
    } else if (y == 2) {
        #pragma unroll 1
        for (int m = 0; m < 2; m++) {
            float* outp = (m == 0 ? psrc : pdst);
            #pragma unroll 1
            for (int oc = 0; oc < 8; oc++) {
                float4 a, c;
                dot2x4<32>(w_s + m * 1024 + oc * 4, hA, hB, a, c);
                *(float4*)(outp + nA*32 + oc*4) = a;
                *(float4*)(outp + nB*32 + oc*4) = c;
            }
        }
    } else {
        #pragma unroll 1
        for (int oc = 0; oc < 8; oc++) {
            float4 a, c;
            dot2x4<32>(w_s + oc * 4, hA, hB, a, c);
            *(float4*)(selfp + nA*32 + oc*4) = a;
            *(float4*)(selfp + nB*32 + oc*4) = c;
        }
    }
}

// ==================== CSR edge kernel: 8 lanes/edge, 4 ch/lane (R14) =======
// R14-verified: uniform bases + node-major rows -> few lines/wave-iter and
// SADDR addressing; 7 gather instructions cover 8 edges.
__global__ __launch_bounds__(256) void edge_csr_k(
    const int2* __restrict__ sorted2, const int* __restrict__ offs,
    const float* __restrict__ psrc, const float* __restrict__ pdst,
    const unsigned* __restrict__ t1b, const unsigned* __restrict__ t2b,
    const uint4* __restrict__ xproj_b, const float* __restrict__ selfp,
    const float* __restrict__ wcomp_l,
    const float* __restrict__ Bw, const float* __restrict__ Bb,
    float* __restrict__ h_next)
{
    // XCD-bijective swizzle: 25000 blocks, 25000 % 8 == 0.
    const int CPX = 25000 / 8;
    int bid = (int)blockIdx.x;
    bid = (bid % 8) * CPX + bid / 8;

    const int wib  = threadIdx.x >> 6;   // wave in block: 0..3
    const int lane = threadIdx.x & 63;
    const int grp  = lane >> 3;          // edge slot 0..7
    const int ci   = lane & 7;           // channel quad 0..7
    const int c4   = ci * 4;
    const int n    = bid * 4 + wib;      // dst node

    const int start = offs[n];
    const int end   = (n == NNODES - 1) ? NEDGES : offs[n + 1];
    const float4 bw = *(const float4*)(Bw + c4);
    const float bb = Bb[0];
    const float4 pd = *(const float4*)(pdst + n * 32 + c4);

    int e = start + grp;
    int2 rec = sorted2[(e < end) ? e : start];
    bool valid = (e < end);

    v2f acc01 = {0.f, 0.f}, acc23 = {0.f, 0.f};
    for (int e0 = start; e0 < end; e0 += 8) {
        int2 cur = rec;
        bool cv = valid;
        int en = e + 8;
        valid = (en < end);
        rec = sorted2[valid ? en : start];
        e = en;

        int s16 = cur.x;             // src*16 (uint4 index base)
        int et  = cur.y & 0xffff;
        int el  = cur.y >> 16;

        float4 ps  = *(const float4*)(psrc + s16 * 2 + c4);
        uint4  xlo = xproj_b[s16 + ci * 2];
        uint4  xhi = xproj_b[s16 + ci * 2 + 1];
        uint2  t1u = *(const uint2*)(t1b + et * 16 + ci * 2);
        uint2  t2u = *(const uint2*)(t2b + el * 16 + ci * 2);
        float4 c   = *(const float4*)(wcomp_l + et * 4);

        v2f t1a = bf2f(t1u.x), t1c = bf2f(t1u.y);
        v2f t2a = bf2f(t2u.x), t2c = bf2f(t2u.y);
        float z0 = fmaxf(ps.x + pd.x + t1a.x + t2a.x, 0.f);
        float z1 = fmaxf(ps.y + pd.y + t1a.y + t2a.y, 0.f);
        float z2 = fmaxf(ps.z + pd.z + t1c.x + t2c.x, 0.f);
        float z3 = fmaxf(ps.w + pd.w + t1c.y + t2c.y, 0.f);
        float d = fmaf(z0, bw.x, fmaf(z1, bw.y, fmaf(z2, bw.z, z3 * bw.w)));
        d = dpp_add<DPP_XOR1>(d);
        d = dpp_add<DPP_XOR2>(d);
        d = dpp_add<DPP_HMIR>(d);
        float a = __builtin_amdgcn_rcpf(1.f + __expf(-(d + bb)));
        a = cv ? a : 0.f;

        v2f b0 = bf2f(xlo.x), b1 = bf2f(xlo.y), b2 = bf2f(xlo.z), b3 = bf2f(xlo.w);
        v2f m01 = c.x * b0 + c.y * b1 + c.z * b2 + c.w * b3;
        v2f g0 = bf2f(xhi.x), g1 = bf2f(xhi.y), g2 = bf2f(xhi.z), g3 = bf2f(xhi.w);
        v2f m23 = c.x * g0 + c.y * g1 + c.z * g2 + c.w * g3;
        acc01 += a * m01;
        acc23 += a * m23;
    }
    // reduce across the 8 edge-slots (off the hot loop)
    #pragma unroll
    for (int s = 8; s <= 32; s <<= 1) {
        acc01.x += __shfl_xor(acc01.x, s);
        acc01.y += __shfl_xor(acc01.y, s);
        acc23.x += __shfl_xor(acc23.x, s);
        acc23.y += __shfl_xor(acc23.y, s);
    }
    if (lane < 8) {
        float4 sp = *(const float4*)(selfp + n * 32 + c4);
        float4 hv;
        hv.x = fmaxf(acc01.x + sp.x, 0.f);
        hv.y = fmaxf(acc01.y + sp.y, 0.f);
        hv.z = fmaxf(acc23.x + sp.z, 0.f);
        hv.w = fmaxf(acc23.y + sp.w, 0.f);
        *(float4*)(h_next + n * 32 + c4) = hv;
    }
}

// ==================== per-graph mean (8 slices) + head/tail (y=8) ==========
__global__ __launch_bounds__(256) void mean_ht_k(
    const float* __restrict__ h, const int* __restrict__ head_ids,
    const int* __restrict__ tail_ids, float* __restrict__ g_acc,
    float* __restrict__ head_buf, float* __restrict__ tail_buf, int l)
{
    int g  = blockIdx.x;
    int sl = blockIdx.y;
    int i  = threadIdx.x & 31;
    if (sl == 8) {
        if (threadIdx.x < 32)
            head_buf[g*96 + l*32 + i] = h[head_ids[g]*32 + i];
        else if (threadIdx.x < 64)
            tail_buf[g*96 + l*32 + i] = h[tail_ids[g]*32 + i];
        return;
    }
    int sub = threadIdx.x >> 5;
    float acc = 0.f;
    for (int k = sub; k < 125; k += 8)
        acc += h[(g*NPER + sl*125 + k)*32 + i];
    __shared__ float red[8][32];
    red[sub][i] = acc;
    __syncthreads();
    if (threadIdx.x < 32) {
        float s2 = 0.f;
        #pragma unroll
        for (int k = 0; k < 8; k++) s2 += red[k][threadIdx.x];
        atomicAdd(&g_acc[g*96 + l*32 + threadIdx.x], s2 * (1.0f/NPER));
    }
}

// ==================== final readout ====================
__global__ __launch_bounds__(64) void readout_k(
    const float* __restrict__ g_acc, const float* __restrict__ head_buf,
    const float* __restrict__ tail_buf, const float* __restrict__ rel_tab,
    const int* __restrict__ rel_labels, const float* __restrict__ fc_w,
    const float* __restrict__ fc_b, float* __restrict__ out)
{
    int g = blockIdx.x;
    int t = threadIdx.x;
    float s = 0.f;
    for (int idx = t; idx < 320; idx += 64) {
        float v;
        if (idx < 96)       v = g_acc[g*96 + idx];
        else if (idx < 192) v = head_buf[g*96 + idx - 96];
        else if (idx < 288) v = tail_buf[g*96 + idx - 192];
        else                v = rel_tab[rel_labels[g]*32 + (idx - 288)];
        s += v * fc_w[idx];
    }
    s += __shfl_xor(s, 1, 64);
    s += __shfl_xor(s, 2, 64);
    s += __shfl_xor(s, 4, 64);
    s += __shfl_xor(s, 8, 64);
    s += __shfl_xor(s, 16, 64);
    s += __shfl_xor(s, 32, 64);
    if (t == 0) out[g] = s + fc_b[0];
}

extern "C" void kernel_launch(void* const* d_in, const int* in_sizes, int n_in,
                              void* d_out, int out_size, void* d_ws, size_t ws_size,
                              hipStream_t stream) {
    const float* feat        = (const float*)d_in[0];
    const float* basis       = (const float*)d_in[1];   // [3,4,32,32]
    const float* w_comp      = (const float*)d_in[2];   // [3,200,4]
    const float* self_loop_w = (const float*)d_in[3];   // [3,32,32]
    const float* A_w         = (const float*)d_in[4];   // [3,128,32]
    const float* A_b         = (const float*)d_in[5];   // [3,32]
    const float* B_w         = (const float*)d_in[6];   // [3,32,1]
    const float* B_b         = (const float*)d_in[7];   // [3,1]
    const float* attn_tab    = (const float*)d_in[8];   // [200,32]
    const float* rel_tab     = (const float*)d_in[9];   // [200,32]
    const float* fc_w        = (const float*)d_in[10];  // [320,1]
    const float* fc_b        = (const float*)d_in[11];  // [1]
    const int* src        = (const int*)d_in[12];
    const int* dst        = (const int*)d_in[13];
    const int* etype      = (const int*)d_in[14];
    const int* elabel     = (const int*)d_in[15];
    const int* head_ids   = (const int*)d_in[17];
    const int* tail_ids   = (const int*)d_in[18];
    const int* rel_labels = (const int*)d_in[19];

    float* ws = (float*)d_ws;
    size_t off = 0;
    float* h0    = ws + off; off += (size_t)NNODES * 32;
    float* h1    = ws + off; off += (size_t)NNODES * 32;
    uint4* xproj_b = (uint4*)(ws + off); off += (size_t)NNODES * 64;  // 256B/node
    float* psrc  = ws + off; off += (size_t)NNODES * 32;
    float* pdst  = ws + off; off += (size_t)NNODES * 32;
    float* selfp = ws + off; off += (size_t)NNODES * 32;
    unsigned* t1b = (unsigned*)(ws + off); off += 3200;
    unsigned* t2b = (unsigned*)(ws + off); off += 3200;
    float* g_acc    = ws + off; off += NGRAPH * 96;
    float* head_buf = ws + off; off += NGRAPH * 96;
    float* tail_buf = ws + off; off += NGRAPH * 96;
    int* count  = (int*)(ws + off); off += NNODES;
    int* offs   = (int*)(ws + off); off += NNODES;
    int* cursor = (int*)(ws + off); off += NNODES;
    off = (off + 3) & ~(size_t)3;               // 16 B align
    int2* sorted2 = (int2*)(ws + off); off += (size_t)NEDGES * 2;

    // ---- one-time per call: CSR by dst + zero mean accumulator ----
    zero2_k<<<(NNODES + 255)/256, 256, 0, stream>>>(count, g_acc);
    hist_k<<<(NEDGES + 255)/256, 256, 0, stream>>>(dst, count);
    scan_k<<<NGRAPH, 1024, 0, stream>>>(count, offs, cursor);
    scatter_k<<<(NEDGES + 255)/256, 256, 0, stream>>>(src, dst, etype, elabel,
                                                      cursor, sorted2);

    const float* hcur = feat;
    float* hbufs[2] = { h0, h1 };
    for (int l = 0; l < 3; l++) {
        dim3 ngrid((NNODES/2 + 255)/256, 5);
        node_k<<<ngrid, 256, 0, stream>>>(
            hcur, basis + (size_t)l*4096, self_loop_w + (size_t)l*1024,
            A_w + (size_t)l*4096, A_b + (size_t)l*32, attn_tab,
            xproj_b, psrc, pdst, selfp, t1b, t2b);
        float* hn = hbufs[l & 1];
        edge_csr_k<<<NNODES/4, 256, 0, stream>>>(
            sorted2, offs, psrc, pdst, t1b, t2b, xproj_b, selfp,
            w_comp + (size_t)l*800, B_w + (size_t)l*32, B_b + l, hn);
        dim3 mgrid(NGRAPH, 9);
        mean_ht_k<<<mgrid, 256, 0, stream>>>(
            hn, head_ids, tail_ids, g_acc, head_buf, tail_buf, l);
        hcur = hn;
    }
    readout_k<<<NGRAPH, 64, 0, stream>>>(
        g_acc, head_buf, tail_buf, rel_tab, rel_labels, fc_w, fc_b, (float*)d_out);
}